// Round 15
// baseline (4292.862 us; speedup 1.0000x reference)
//
#include <hip/hip_runtime.h>
#include <hip/hip_bf16.h>
#include <math.h>

// ConvLSTMClassifier on MI355X — per-step MFMA, 4 blocks/CU, barrier-free
// GEMM: A staged via global_load_lds (swizzle baked into global addr),
// B register-staged from L2 with compiler-scheduled pipelining.
// gates[b,w,n] = bias[n] + sum_kx x[b,t,w+kx-1]*pxw[kx,n]
//              + sum_kx sum_ic h[b,w+kx-1,ic]*Bp[kx,n,ic],  n = g*128+ch.
// h: bf16 [B][W+2][CH], guard rows w=-1,512 permanently zero.
// c: bf16 [B][W][CH], epilogue-only.
// Block: 256 thr / 4 waves; tile M=64 x N=256 (4 gates x 64 ch).
// grid (8, 2, 64) = 1024 blocks = 4/CU. LDS 17.2 KB. One barrier per step.
// 128 launches + fc_final.

constexpr int kB  = 64;
constexpr int kCH = 128;
constexpr int kH  = 128;
constexpr int kW  = 512;
constexpr int kNC = 10;
constexpr int kWP = kW + 2;  // padded h rows (guards at w=-1, w=512)

typedef __attribute__((ext_vector_type(8))) short short8v;
typedef __attribute__((ext_vector_type(4))) float float4v;

__device__ __forceinline__ float fsig(float v) {
    return 1.0f / (1.0f + __expf(-v));
}
__device__ __forceinline__ float ftanh(float v) {
    float e = __expf(2.0f * v);
    return 1.0f - 2.0f / (e + 1.0f);
}
__device__ __forceinline__ float bf_to_f32(unsigned short u) {
    unsigned int t = (unsigned int)u << 16;
    return *reinterpret_cast<float*>(&t);
}
__device__ __forceinline__ unsigned short f32_to_bf(float f) {
    __hip_bfloat16 h = __float2bfloat16(f);
    return *reinterpret_cast<unsigned short*>(&h);
}

// ---------------------------------------------------------------------------
// Weight pack + guard-row zeroing + pooled zeroing.
// ---------------------------------------------------------------------------
__global__ __launch_bounds__(256) void pack_weights(
    const float* __restrict__ conv_w,  // [512][129][3][3]
    const float* __restrict__ conv_b,  // [512]
    short* __restrict__ Bp,            // [3][512][128]
    float* __restrict__ pxw,           // [3][512]
    float* __restrict__ pb,            // [512]
    float* __restrict__ pooled,        // [64][128]
    unsigned short* __restrict__ hA,   // [B][W+2][CH]
    unsigned short* __restrict__ hB)   // [B][W+2][CH]
{
    int idx = blockIdx.x * 256 + threadIdx.x;
    if (idx < 3 * 512 * 128) {
        int ic = idx & 127;
        int oc = (idx >> 7) & 511;
        int kx = idx >> 16;
        float v = conv_w[((oc * 129 + 1 + ic) * 3 + 1) * 3 + kx];
        __hip_bfloat16 hv = __float2bfloat16(v);
        Bp[idx] = *reinterpret_cast<short*>(&hv);
    }
    if (idx < 3 * 512) {
        int oc = idx & 511, kx = idx >> 9;
        pxw[idx] = conv_w[((oc * 129 + 0) * 3 + 1) * 3 + kx];
    }
    if (idx < 512) pb[idx] = conv_b[idx];
    if (idx < kB * kCH) pooled[idx] = 0.0f;
    // zero guard rows (w=-1 -> padded row 0, w=512 -> padded row 513)
    if (idx < kB * 2 * kCH) {
        int b  = idx >> 8;
        int r  = (idx >> 7) & 1;
        int ch = idx & 127;
        size_t off = ((size_t)b * kWP + (r ? (kWP - 1) : 0)) * kCH + ch;
        hA[off] = 0;
        hB[off] = 0;
    }
}

// ---------------------------------------------------------------------------
// One LSTM step. grid = (8 wtiles, 2 cht, 64 b), block = 256 (4 waves).
// ---------------------------------------------------------------------------
template <bool FIRST, bool LAST>
__global__ __launch_bounds__(256, 4) void lstm_step(
    const float* __restrict__ x,              // [B][1][H][W]
    const short* __restrict__ Bp,             // [3][512][128]
    const float* __restrict__ pxw,            // [3][512]
    const float* __restrict__ pb,             // [512]
    const unsigned short* __restrict__ hIn,   // [B][W+2][CH] bf16, guarded
    unsigned short* __restrict__ hOut,        // [B][W+2][CH] bf16, guarded
    const unsigned short* __restrict__ cIn,   // [B][W][CH] bf16
    unsigned short* __restrict__ cOut,        // [B][W][CH] bf16
    float* __restrict__ pooled,               // [B][CH]
    int t)
{
    __shared__ alignas(16) short S[66 * 128];  // h slab, swizzled (16.9 KB)
    __shared__ float xs[66];

    const int tid  = threadIdx.x;
    const int lane = tid & 63;
    const int wave = tid >> 6;          // 0..3 = 16-ch slice within cht-half
    const int w0   = blockIdx.x * 64;
    const int cht  = blockIdx.y;        // ch-half
    const int b    = blockIdx.z;

    const int ncol = lane & 15;
    const int krow = lane >> 4;
    const int ch   = cht * 64 + wave * 16 + ncol;  // 0..127

    const size_t hbase = (size_t)b * kWP * kCH;  // padded-h base
    const size_t cbase = (size_t)b * kW * kCH;   // c base

    // ---- staging: x strip (VALU path) + A slab via global_load_lds ----
    for (int i = tid; i < 66; i += 256) {
        int w = w0 - 1 + i;
        xs[i] = (w >= 0 && w < kW)
              ? x[((size_t)b * kH + t) * kW + w] : 0.0f;
    }
    if (!FIRST) {
        // A slab: LDS (row, slot) holds global col = slot^(row&7); linear
        // LDS dest, swizzle baked into the per-lane global source address.
        for (int i = tid; i < 66 * 16; i += 256) {
            int row  = i >> 4, slot = i & 15;
            int col  = slot ^ (row & 7);
            int w    = w0 - 1 + row;            // in [-1, 512]: guards cover
            __builtin_amdgcn_global_load_lds(
                (const unsigned int*)(hIn + hbase + (size_t)(w + 1) * kCH + col * 8),
                (unsigned int*)(S + i * 8), 16, 0, 0);
        }
    }
    __syncthreads();  // the ONLY barrier in this kernel

    // ---- GEMM: fully unrolled, B register-staged (compiler pipelines) ----
    float4v acc[4][4];  // [mfrag][gate]
#pragma unroll
    for (int mf = 0; mf < 4; ++mf)
#pragma unroll
        for (int g = 0; g < 4; ++g)
            acc[mf][g] = float4v{0.f, 0.f, 0.f, 0.f};

    if (!FIRST) {
        const short* Bbase = Bp + ch * 128 + krow * 8;  // + kx*65536 + g*16384 + ks*32
#pragma unroll
        for (int kq = 0; kq < 12; ++kq) {
            const int kx = kq >> 2, ks = kq & 3;
            short8v bfr[4];
#pragma unroll
            for (int g = 0; g < 4; ++g)
                bfr[g] = *reinterpret_cast<const short8v*>(
                    Bbase + kx * 65536 + g * 16384 + ks * 32);
            short8v afr[4];
#pragma unroll
            for (int mf = 0; mf < 4; ++mf) {
                int srow = mf * 16 + ncol + kx;
                int slot = (ks * 4 + krow) ^ (srow & 7);
                afr[mf] = *reinterpret_cast<const short8v*>(
                    S + srow * 128 + slot * 8);
            }
#pragma unroll
            for (int mf = 0; mf < 4; ++mf)
#pragma unroll
                for (int g = 0; g < 4; ++g)
                    acc[mf][g] = __builtin_amdgcn_mfma_f32_16x16x32_bf16(
                        afr[mf], bfr[g], acc[mf][g], 0, 0, 0);
        }
    }

    // ---- epilogue (r10-proven math) ----
    float wxk[4][3], bia[4];
#pragma unroll
    for (int g = 0; g < 4; ++g) {
        bia[g] = pb[g * 128 + ch];
#pragma unroll
        for (int kx = 0; kx < 3; ++kx)
            wxk[g][kx] = pxw[kx * 512 + g * 128 + ch];
    }

    float psum = 0.0f;
#pragma unroll
    for (int mf = 0; mf < 4; ++mf) {
        unsigned short cu[4];
        if (!FIRST) {
#pragma unroll
            for (int r = 0; r < 4; ++r) {
                int m = mf * 16 + krow * 4 + r;
                cu[r] = cIn[cbase + (size_t)(w0 + m) * kCH + ch];
            }
        }
#pragma unroll
        for (int r = 0; r < 4; ++r) {
            int m = mf * 16 + krow * 4 + r;
            float xm = xs[m], xc = xs[m + 1], xp = xs[m + 2];
            float v0 = acc[mf][0][r] + bia[0] + xm * wxk[0][0] + xc * wxk[0][1] + xp * wxk[0][2];
            float v1 = acc[mf][1][r] + bia[1] + xm * wxk[1][0] + xc * wxk[1][1] + xp * wxk[1][2];
            float v2 = acc[mf][2][r] + bia[2] + xm * wxk[2][0] + xc * wxk[2][1] + xp * wxk[2][2];
            float v3 = acc[mf][3][r] + bia[3] + xm * wxk[3][0] + xc * wxk[3][1] + xp * wxk[3][2];
            float cprev = FIRST ? 0.0f : bf_to_f32(cu[r]);
            float si = fsig(v0);
            float sf = fsig(v1);
            float tg = ftanh(v2);
            float so = fsig(v3);
            float cn = sf * cprev + si * tg;
            float hn = so * ftanh(cn);
            if (LAST) {
                psum += hn;
            } else {
                hOut[hbase + (size_t)(w0 + m + 1) * kCH + ch] = f32_to_bf(hn);
                cOut[cbase + (size_t)(w0 + m) * kCH + ch]     = f32_to_bf(cn);
            }
        }
    }

    if (LAST) {
        psum += __shfl_xor(psum, 16, 64);
        psum += __shfl_xor(psum, 32, 64);
        if (krow == 0) atomicAdd(&pooled[b * kCH + ch], psum);
    }
}

// ---------------------------------------------------------------------------
// Final FC from pooled sums. grid = B, block = 64.
// ---------------------------------------------------------------------------
__global__ __launch_bounds__(64) void fc_final(
    const float* __restrict__ pooled,  // [B][CH] raw sums over W
    const float* __restrict__ fc_w,    // [NC][CH]
    const float* __restrict__ fc_b,    // [NC]
    float* __restrict__ out)           // [B][NC]
{
    int b = blockIdx.x, nc = threadIdx.x;
    if (nc < kNC) {
        float s = 0.0f;
        for (int k = 0; k < kCH; ++k)
            s = fmaf(pooled[b * kCH + k], fc_w[nc * kCH + k], s);
        out[b * kNC + nc] = fc_b[nc] + s * (1.0f / kW);
    }
}

// ---------------------------------------------------------------------------
extern "C" void kernel_launch(void* const* d_in, const int* in_sizes, int n_in,
                              void* d_out, int out_size, void* d_ws, size_t ws_size,
                              hipStream_t stream) {
    const float* x      = (const float*)d_in[0];
    const float* conv_w = (const float*)d_in[1];
    const float* conv_b = (const float*)d_in[2];
    const float* fc_w   = (const float*)d_in[3];
    const float* fc_b   = (const float*)d_in[4];
    float* out = (float*)d_out;

    const size_t hN = (size_t)kB * kWP * kCH;  // padded h
    const size_t cN = (size_t)kB * kW * kCH;
    unsigned short* hA = (unsigned short*)d_ws;
    unsigned short* hB = hA + hN;
    unsigned short* cA = hB + hN;
    unsigned short* cB = cA + cN;
    short* Bp          = (short*)(cB + cN);
    float* pxw         = (float*)(Bp + 3 * 512 * 128);
    float* pb          = pxw + 3 * 512;
    float* pooled      = pb + 512;  // [64][128]

    pack_weights<<<768, 256, 0, stream>>>(conv_w, conv_b, Bp, pxw, pb, pooled,
                                          hA, hB);

    dim3 grid(kW / 64, 2, kB);
    dim3 block(256);
    // write(t) = t even ? (hB,cB) : (hA,cA); read(t) = write(t-1).
    lstm_step<true, false><<<grid, block, 0, stream>>>(
        x, Bp, pxw, pb, hA, hB, cA, cB, pooled, 0);
    for (int t = 1; t < kH - 1; ++t) {
        const unsigned short* hi = (t & 1) ? hB : hA;
        unsigned short*       ho = (t & 1) ? hA : hB;
        const unsigned short* ci = (t & 1) ? cB : cA;
        unsigned short*       co = (t & 1) ? cA : cB;
        lstm_step<false, false><<<grid, block, 0, stream>>>(
            x, Bp, pxw, pb, hi, ho, ci, co, pooled, t);
    }
    // t = 127 (odd): reads write(126) = (hB,cB); outputs pooled only.
    lstm_step<false, true><<<grid, block, 0, stream>>>(
        x, Bp, pxw, pb, hB, hA, cB, cA, pooled, 127);

    fc_final<<<kB, 64, 0, stream>>>(pooled, fc_w, fc_b, out);
}